// Round 16
// baseline (58.522 us; speedup 1.0000x reference)
//
#include <hip/hip_runtime.h>
#include <math.h>

// Problem constants: B=4, C=128, H=W=96, E=4, C8=16, scale=2 (baked in)
#define Bn 4
#define Cc 128
#define Hh 96
#define Ww 96
#define H2c 192
#define W2c 192
#define HW (Hh*Ww)
#define HW2 (H2c*W2c)

// Workspace: floats [0,16) = per-class taps {tx,ty,Dx,Dy};
//            ushort Mw at float-offset 16: M[cls][c_out][128] (We*Wc + I, bf16)
#define TAP_OFF 0
#define M_OFF 16

typedef float  f32x4  __attribute__((ext_vector_type(4)));
typedef short  s16x8  __attribute__((ext_vector_type(8)));

__device__ __forceinline__ unsigned f2bf(float f) {
    unsigned u = __float_as_uint(f);
    return (u + 0x7FFFu + ((u >> 16) & 1u)) >> 16;   // RNE to bf16
}

// global -> LDS DMA, 16B per lane. LDS dest = wave-uniform base + lane*16.
__device__ __forceinline__ void gload_lds16(const float* g, float* l) {
    __builtin_amdgcn_global_load_lds(
        (const __attribute__((address_space(1))) unsigned int*)g,
        (__attribute__((address_space(3))) unsigned int*)l, 16, 0, 0);
}

// ---------------------------------------------------------------------------
// K1 (fused, verified r15): per-class MLP -> taps AND M[cls] = We_mix*Wc_mix + I
// from GLOBAL wcomp/wexp. 64 blocks x 256 threads.
__global__ __launch_bounds__(256) void k1_prep(
    const float* __restrict__ wcomp, const float* __restrict__ wexp,
    const float* __restrict__ bw1, const float* __restrict__ bb1,
    const float* __restrict__ bw2, const float* __restrict__ bb2,
    const float* __restrict__ rw,  const float* __restrict__ rb,
    const float* __restrict__ ow,  const float* __restrict__ ob,
    float* __restrict__ ws, unsigned short* __restrict__ Mw)
{
    __shared__ float e1[64], e2[64], rr4[4], of2[2];
    const int tid   = threadIdx.x;
    const int cls   = blockIdx.x >> 4;
    const int chunk = blockIdx.x & 15;
    const float chv = (cls & 2) ? 0.25f : -0.25f;
    const float cwv = (cls & 1) ? 0.25f : -0.25f;

    if (tid < 64) {
        float h = bw1[tid*3+0]*0.5f + bw1[tid*3+1]*chv + bw1[tid*3+2]*cwv + bb1[tid];
        e1[tid] = fmaxf(h, 0.f);
    }
    __syncthreads();
    if (tid < 64) {
        float s = bb2[tid];
        for (int i = 0; i < 64; ++i) s += bw2[tid*64+i]*e1[i];
        e2[tid] = fmaxf(s, 0.f);
    }
    __syncthreads();
    if (tid < 6) {
        if (tid < 4) {
            float s = rb[tid];
            for (int i = 0; i < 64; ++i) s += rw[tid*64+i]*e2[i];
            rr4[tid] = 1.f/(1.f+expf(-s));
        } else {
            const int d = tid - 4;
            float s = ob[d];
            for (int i = 0; i < 64; ++i) s += ow[d*64+i]*e2[i];
            of2[d] = s;
        }
    }
    __syncthreads();
    const float r0 = rr4[0], r1 = rr4[1], r2 = rr4[2], r3 = rr4[3];

    if (chunk == 0 && tid == 0) {
        const float fx = cwv + of2[0];
        const float fy = chv + of2[1];
        const float Dx = floorf(fx), Dy = floorf(fy);
        ws[TAP_OFF + cls*4 + 0] = fx - Dx;
        ws[TAP_OFF + cls*4 + 1] = fy - Dy;
        ws[TAP_OFF + cls*4 + 2] = Dx;
        ws[TAP_OFF + cls*4 + 3] = Dy;
    }

    // M slice: thread -> (co, ci0..+3). wexp[e][c][o]: e*2048+c*16+o;
    // wcomp[e][o][c]: e*2048+o*128+c.
    const int co  = chunk*8 + (tid >> 5);
    const int ci0 = (tid & 31) * 4;
    const float* weB = wexp + co*16;
    float wem[16];
    #pragma unroll
    for (int o = 0; o < 16; ++o)
        wem[o] = r0*weB[o] + r1*weB[2048+o] + r2*weB[4096+o] + r3*weB[6144+o];
    float m[4];
    #pragma unroll
    for (int q = 0; q < 4; ++q) {
        const int ci = ci0 + q;
        const float* wcB = wcomp + ci;
        float s = 0.f;
        #pragma unroll
        for (int o = 0; o < 16; ++o) {
            const float wcm = r0*wcB[o*128]        + r1*wcB[2048 + o*128]
                            + r2*wcB[4096 + o*128] + r3*wcB[6144 + o*128];
            s += wem[o]*wcm;
        }
        if (co == ci) s += 1.f;
        m[q] = s;
    }
    uint2 v;
    v.x = f2bf(m[0]) | (f2bf(m[1]) << 16);
    v.y = f2bf(m[2]) | (f2bf(m[3]) << 16);
    *reinterpret_cast<uint2*>(Mw + (size_t)cls*16384 + co*128 + ci0) = v;
}

// Edge remap (verified rounds 1-15).
__device__ __forceinline__ void remap_axis(int c0, int last, float w0, float w1,
                                           int& base, float& a0, float& a1)
{
    base = min(max(c0, 0), last - 1);
    if (c0 >= 0 && c0 < last) { a0 = w0;  a1 = w1;  }
    else if (c0 == -1)        { a0 = w1;  a1 = 0.f; }
    else if (c0 == last)      { a0 = 0.f; a1 = w0;  }
    else                      { a0 = 0.f; a1 = 0.f; }
}

// ---------------------------------------------------------------------------
// K2: TWIN concurrent pipelines per block. 1152 blocks x 512 threads (8 waves).
// Sub-group sg = tid>>8 handles x-parity class (base&1 -> py, sg -> px) of the
// SAME spatial tile, running r12's DMA-pipelined producer + MFMA GEMM verbatim
// on its own lF/lWin. The twins share only __syncthreads at identical points.
// Twin stores fill complementary stride-2 halves of every 64B line in-block.
__global__ __launch_bounds__(512, 4) void k2_mfma(
    const float* __restrict__ x, const float* __restrict__ wsr,
    const unsigned short* __restrict__ Mw, float* __restrict__ out)
{
    __shared__ __align__(16) unsigned short lF[2*64*128];  // 32 KB: [sg] fea tiles
    __shared__ __align__(16) float lWin[8*1024];           // 32 KB: [wave][buf][512]

    const int tid = threadIdx.x;
    const int xl  = tid & 63;
    const int grp = (tid >> 6) & 3;
    const int sg  = tid >> 8;

    // XCD swizzle: 1152 = 8 XCDs * 144; twin classes inside the block.
    const int n    = blockIdx.x;
    const int base = (n & 7)*144 + (n >> 3);      // 0..1151
    const int w    = base*2 + sg;                 // 0..2303, r12's work index
    const int cls  = w & 3;
    const int px_  = cls & 1, py = (cls >> 1) & 1;
    const int rest = w >> 2;          // 0..575
    const int tile = rest % 144;
    const int b    = rest / 144;
    const int jt = tile/3, xs = tile - jt*3;
    const int j0 = jt*2, i0 = xs*32;  // class-tile origin (half-res)

    unsigned short* lFs = lF + sg*8192;

    // ---- A fragments: M rows for this wave's 32 out-channels ----
    const unsigned short* Mc = Mw + (size_t)cls*16384;
    const int lo = xl & 15, hi = xl >> 4;
    s16x8 a[2][4];
    #pragma unroll
    for (int t = 0; t < 2; ++t)
        #pragma unroll
        for (int kk = 0; kk < 4; ++kk)
            a[t][kk] = *reinterpret_cast<const s16x8*>(
                Mc + (32*grp + 16*t + lo)*128 + kk*32 + hi*8);

    // ---- per-pixel tap constants (lane = pixel slot) ----
    const int pr = xl >> 5, pc = xl & 31;
    const int j = j0 + pr, i = i0 + pc;

    const float tx = wsr[TAP_OFF + cls*4 + 0];
    const float ty = wsr[TAP_OFF + cls*4 + 1];
    const int   Dx = (int)wsr[TAP_OFF + cls*4 + 2];
    const int   Dy = (int)wsr[TAP_OFF + cls*4 + 3];
    int basex, basey; float ax0, ax1, ay0, ay1;
    remap_axis(i + Dx, Ww - 1, 1.f - tx, tx, basex, ax0, ax1);
    remap_axis(j + Dy, Hh - 1, 1.f - ty, ty, basey, ay0, ay1);
    const float w00 = ay0*ax0, w01 = ay0*ax1, w10 = ay1*ax0, w11 = ay1*ax1;

    // window geometry (verified r11/r12)
    const int c0  = i0 + Dx;
    const int cs0 = min(max(0, c0 & ~3), Ww - 40);
    const int cidx = basex - cs0;
    const int ro0 = pr*40 + cidx;
    const int ro1 = ro0 + 40;

    // staging lane assignment (verified r11/r12)
    const int jD = j0 + Dy;
    const int sl = xl & 31;
    const int s2 = min(sl, 29);
    const int lr = s2 / 10, lq = s2 - lr*10;
    const int lrow = min(max(jD + lr, 0), Hh - 1);
    const float* gsrc = x + (size_t)b*Cc*HW + (size_t)lrow*Ww + cs0 + 4*lq;
    const int chsub = xl >> 5;

    float* winw = lWin + (tid >> 6)*1024;   // this wave's 2 x 512-float buffers

#define ISSUE(q) { \
    _Pragma("unroll") \
    for (int p = 0; p < 2; ++p) \
        gload_lds16(gsrc + (size_t)(grp*32 + (q)*4 + p*2 + chsub)*HW, \
                    winw + ((q)&1)*512 + p*256); }

    // ---- 8-chunk pipeline, 2 chunks in flight, counted vmcnt (r12 verbatim) ----
    ISSUE(0)
    ISSUE(1)
    #pragma unroll
    for (int q = 0; q < 8; ++q) {
        if (q < 7) asm volatile("s_waitcnt vmcnt(2)" ::: "memory");
        else       asm volatile("s_waitcnt vmcnt(0)" ::: "memory");
        __builtin_amdgcn_sched_barrier(0);
        {
            const float* wb = winw + (q&1)*512;
            float f[4];
            #pragma unroll
            for (int u = 0; u < 4; ++u) {
                const float* wc = wb + (u>>1)*256 + (u&1)*128;
                f[u] = w00*wc[ro0] + w01*wc[ro0+1] + w10*wc[ro1] + w11*wc[ro1+1];
            }
            uint2 v;
            v.x = f2bf(f[0]) | (f2bf(f[1]) << 16);
            v.y = f2bf(f[2]) | (f2bf(f[3]) << 16);
            const int c = grp*32 + q*4;
            int byte = xl*256 + c*2;
            byte ^= (xl & 7) << 4;
            *reinterpret_cast<uint2*>(reinterpret_cast<char*>(lFs) + byte) = v;
        }
        if (q < 6) {
            asm volatile("s_waitcnt lgkmcnt(0)" ::: "memory");
            __builtin_amdgcn_sched_barrier(0);
            ISSUE(q+2)
        }
    }
#undef ISSUE
    __syncthreads();

    // ---- GEMM: D[128ch x 64px] = M @ fea (residual folded into M) ----
    f32x4 acc[2][4];
    #pragma unroll
    for (int t = 0; t < 2; ++t)
        #pragma unroll
        for (int nn = 0; nn < 4; ++nn) acc[t][nn] = (f32x4){0.f, 0.f, 0.f, 0.f};

    #pragma unroll
    for (int kk = 0; kk < 4; ++kk) {
        #pragma unroll
        for (int nn = 0; nn < 4; ++nn) {
            int byte = (nn*16 + lo)*256 + kk*64 + hi*16;
            byte ^= (lo & 7) << 4;
            const s16x8 bf = *reinterpret_cast<const s16x8*>(
                reinterpret_cast<const char*>(lFs) + byte);
            acc[0][nn] = __builtin_amdgcn_mfma_f32_16x16x32_bf16(a[0][kk], bf, acc[0][nn], 0, 0, 0);
            acc[1][nn] = __builtin_amdgcn_mfma_f32_16x16x32_bf16(a[1][kk], bf, acc[1][nn], 0, 0, 0);
        }
    }

    // ---- store (r7/r11 pattern; twin fills the complementary stride-2 half) ----
    #pragma unroll
    for (int t = 0; t < 2; ++t)
        #pragma unroll
        for (int nn = 0; nn < 4; ++nn) {
            const int slot2 = nn*16 + lo;
            const int pr2 = slot2 >> 5, pc2 = slot2 & 31;
            const int yg = 2*(j0 + pr2) + py;
            const int xg = 2*(i0 + pc2) + px_;
            const int ch0 = 32*grp + 16*t + hi*4;
            float* op = out + ((size_t)(b*Cc + ch0)*H2c + yg)*W2c + xg;
            #pragma unroll
            for (int r = 0; r < 4; ++r)
                op[(size_t)r*HW2] = acc[t][nn][r];
        }
}

extern "C" void kernel_launch(void* const* d_in, const int* in_sizes, int n_in,
                              void* d_out, int out_size, void* d_ws, size_t ws_size,
                              hipStream_t stream) {
    const float* x     = (const float*)d_in[0];
    const float* wcomp = (const float*)d_in[1];
    const float* wexp  = (const float*)d_in[2];
    const float* bw1   = (const float*)d_in[3];
    const float* bb1   = (const float*)d_in[4];
    const float* bw2   = (const float*)d_in[5];
    const float* bb2   = (const float*)d_in[6];
    const float* rw    = (const float*)d_in[7];
    const float* rb    = (const float*)d_in[8];
    const float* ow    = (const float*)d_in[9];
    const float* ob    = (const float*)d_in[10];
    float* out = (float*)d_out;
    float* ws  = (float*)d_ws;
    unsigned short* Mw = (unsigned short*)(ws + M_OFF);   // ~128 KB used

    k1_prep<<<64, 256, 0, stream>>>(wcomp, wexp, bw1, bb1, bw2, bb2,
                                    rw, rb, ow, ob, ws, Mw);
    k2_mfma<<<1152, 512, 0, stream>>>(x, ws, Mw, out);
}

// Round 17
// 58.332 us; speedup vs baseline: 1.0033x; 1.0033x over previous
//
#include <hip/hip_runtime.h>
#include <math.h>

// Problem constants: B=4, C=128, H=W=96, E=4, C8=16, scale=2 (baked in)
#define Bn 4
#define Cc 128
#define Hh 96
#define Ww 96
#define H2c 192
#define W2c 192
#define HW (Hh*Ww)
#define HW2 (H2c*W2c)

// Workspace: floats [0,16) = per-class taps {tx,ty,Dx,Dy};
//            ushort Mw at float-offset 16: M[cls][c_out][128] (We*Wc + I, bf16)
#define TAP_OFF 0
#define M_OFF 16

typedef float  f32x4  __attribute__((ext_vector_type(4)));
typedef short  s16x8  __attribute__((ext_vector_type(8)));

__device__ __forceinline__ unsigned f2bf(float f) {
    unsigned u = __float_as_uint(f);
    return (u + 0x7FFFu + ((u >> 16) & 1u)) >> 16;   // RNE to bf16
}

// global -> LDS DMA, 16B per lane. LDS dest = wave-uniform base + lane*16.
__device__ __forceinline__ void gload_lds16(const float* g, float* l) {
    __builtin_amdgcn_global_load_lds(
        (const __attribute__((address_space(1))) unsigned int*)g,
        (__attribute__((address_space(3))) unsigned int*)l, 16, 0, 0);
}

// ---------------------------------------------------------------------------
// K1 (fused, verified r15/r16): per-class MLP -> taps AND
// M[cls] = We_mix*Wc_mix + I from GLOBAL wcomp/wexp. 64 blocks x 256 threads.
__global__ __launch_bounds__(256) void k1_prep(
    const float* __restrict__ wcomp, const float* __restrict__ wexp,
    const float* __restrict__ bw1, const float* __restrict__ bb1,
    const float* __restrict__ bw2, const float* __restrict__ bb2,
    const float* __restrict__ rw,  const float* __restrict__ rb,
    const float* __restrict__ ow,  const float* __restrict__ ob,
    float* __restrict__ ws, unsigned short* __restrict__ Mw)
{
    __shared__ float e1[64], e2[64], rr4[4], of2[2];
    const int tid   = threadIdx.x;
    const int cls   = blockIdx.x >> 4;
    const int chunk = blockIdx.x & 15;
    const float chv = (cls & 2) ? 0.25f : -0.25f;
    const float cwv = (cls & 1) ? 0.25f : -0.25f;

    if (tid < 64) {
        float h = bw1[tid*3+0]*0.5f + bw1[tid*3+1]*chv + bw1[tid*3+2]*cwv + bb1[tid];
        e1[tid] = fmaxf(h, 0.f);
    }
    __syncthreads();
    if (tid < 64) {
        float s = bb2[tid];
        for (int i = 0; i < 64; ++i) s += bw2[tid*64+i]*e1[i];
        e2[tid] = fmaxf(s, 0.f);
    }
    __syncthreads();
    if (tid < 6) {
        if (tid < 4) {
            float s = rb[tid];
            for (int i = 0; i < 64; ++i) s += rw[tid*64+i]*e2[i];
            rr4[tid] = 1.f/(1.f+expf(-s));
        } else {
            const int d = tid - 4;
            float s = ob[d];
            for (int i = 0; i < 64; ++i) s += ow[d*64+i]*e2[i];
            of2[d] = s;
        }
    }
    __syncthreads();
    const float r0 = rr4[0], r1 = rr4[1], r2 = rr4[2], r3 = rr4[3];

    if (chunk == 0 && tid == 0) {
        const float fx = cwv + of2[0];
        const float fy = chv + of2[1];
        const float Dx = floorf(fx), Dy = floorf(fy);
        ws[TAP_OFF + cls*4 + 0] = fx - Dx;
        ws[TAP_OFF + cls*4 + 1] = fy - Dy;
        ws[TAP_OFF + cls*4 + 2] = Dx;
        ws[TAP_OFF + cls*4 + 3] = Dy;
    }

    // M slice: thread -> (co, ci0..+3). wexp[e][c][o]: e*2048+c*16+o;
    // wcomp[e][o][c]: e*2048+o*128+c.
    const int co  = chunk*8 + (tid >> 5);
    const int ci0 = (tid & 31) * 4;
    const float* weB = wexp + co*16;
    float wem[16];
    #pragma unroll
    for (int o = 0; o < 16; ++o)
        wem[o] = r0*weB[o] + r1*weB[2048+o] + r2*weB[4096+o] + r3*weB[6144+o];
    float m[4];
    #pragma unroll
    for (int q = 0; q < 4; ++q) {
        const int ci = ci0 + q;
        const float* wcB = wcomp + ci;
        float s = 0.f;
        #pragma unroll
        for (int o = 0; o < 16; ++o) {
            const float wcm = r0*wcB[o*128]        + r1*wcB[2048 + o*128]
                            + r2*wcB[4096 + o*128] + r3*wcB[6144 + o*128];
            s += wem[o]*wcm;
        }
        if (co == ci) s += 1.f;
        m[q] = s;
    }
    uint2 v;
    v.x = f2bf(m[0]) | (f2bf(m[1]) << 16);
    v.y = f2bf(m[2]) | (f2bf(m[3]) << 16);
    *reinterpret_cast<uint2*>(Mw + (size_t)cls*16384 + co*128 + ci0) = v;
}

// Edge remap (verified rounds 1-16).
__device__ __forceinline__ void remap_axis(int c0, int last, float w0, float w1,
                                           int& base, float& a0, float& a1)
{
    base = min(max(c0, 0), last - 1);
    if (c0 >= 0 && c0 < last) { a0 = w0;  a1 = w1;  }
    else if (c0 == -1)        { a0 = w1;  a1 = 0.f; }
    else if (c0 == last)      { a0 = 0.f; a1 = w0;  }
    else                      { a0 = 0.f; a1 = 0.f; }
}

// ---------------------------------------------------------------------------
// K2: r13's both-parity kernel (producer + GEMM verbatim, correctness-proven)
// with an LDS-TRANSPOSED EPILOGUE: accumulators -> lO[ch][xgl] (32 KB union
// over lWin/lF) -> fully coalesced dwordx4 stores (64 lanes = 4 complete
// 256 B channel-rows per instruction; full 64 B lines, no cross-block merge).
__global__ __launch_bounds__(256) void k2_mfma(
    const float* __restrict__ x, const float* __restrict__ wsr,
    const unsigned short* __restrict__ Mw, float* __restrict__ out)
{
    __shared__ __align__(16) char ldsu[32768];   // union: lWin(16K)+lF(16K) / lO(32K)
    float*          lWin = reinterpret_cast<float*>(ldsu);
    unsigned short* lF   = reinterpret_cast<unsigned short*>(ldsu + 16384);

    const int tid = threadIdx.x;
    const int xl  = tid & 63;
    const int grp = tid >> 6;

    // XCD swizzle (r13): 2304 = 8 XCDs * 288.
    const int n  = blockIdx.x;
    const int w  = (n & 7)*288 + (n >> 3);
    const int b  = w / 576;
    const int rr = w % 576;
    const int yg = rr / 3;            // full-res row 0..191
    const int xt = rr % 3;            // 64-px x-strip
    const int ygp = yg & 1;
    const int j   = yg >> 1;          // half-res row
    const int i0  = xt*32;            // half-res col base
    const int clsE = ygp << 1;        // even-x class; odd = clsE|1

    // ---- per-lane pixel: px = xl&1, half-res col i = i0 + (xl>>1) ----
    const int px = xl & 1;
    const int i  = i0 + (xl >> 1);

    const float txE = wsr[TAP_OFF + clsE*4 + 0], txO = wsr[TAP_OFF + (clsE|1)*4 + 0];
    const float tyE = wsr[TAP_OFF + clsE*4 + 1], tyO = wsr[TAP_OFF + (clsE|1)*4 + 1];
    const int   DxE = (int)wsr[TAP_OFF + clsE*4 + 2], DxO = (int)wsr[TAP_OFF + (clsE|1)*4 + 2];
    const int   DyE = (int)wsr[TAP_OFF + clsE*4 + 3], DyO = (int)wsr[TAP_OFF + (clsE|1)*4 + 3];
    const float tx = px ? txO : txE;
    const float ty = px ? tyO : tyE;
    const int   Dx = px ? DxO : DxE;
    const int   Dy = px ? DyO : DyE;

    int basex, basey; float ax0, ax1, ay0, ay1;
    remap_axis(i + Dx, Ww - 1, 1.f - tx, tx, basex, ax0, ax1);
    remap_axis(j + Dy, Hh - 1, 1.f - ty, ty, basey, ay0, ay1);
    const float w00 = ay0*ax0, w01 = ay0*ax1, w10 = ay1*ax0, w11 = ay1*ax1;

    // shared window for BOTH classes: 3 rows x 40 cols from the min corner
    const int minDx = min(DxE, DxO), minDy = min(DyE, DyO);
    const int cs0 = min(max((i0 + minDx) & ~3, 0), Ww - 40);
    const int jDc = min(j + minDy, Hh - 2);
    const int ro0 = (basey - jDc)*40 + (basex - cs0);
    const int ro1 = ro0 + 40;

    // staging lane assignment (verified r11-r13)
    const int sl = xl & 31, s2 = min(sl, 29);
    const int lr = s2 / 10, lq = s2 - lr*10;
    const int lrow = min(max(jDc + lr, 0), Hh - 1);
    const float* gsrc = x + (size_t)b*Cc*HW + (size_t)lrow*Ww + cs0 + 4*lq;
    const int chsub = xl >> 5;

    float* winw = lWin + grp*1024;    // this wave's 2 x 512-float buffers
    const int slot = px*32 + (xl >> 1);   // LDS pixel slot (class-pure halves)

#define ISSUE(q) { \
    _Pragma("unroll") \
    for (int p = 0; p < 2; ++p) \
        gload_lds16(gsrc + (size_t)(grp*32 + (q)*4 + p*2 + chsub)*HW, \
                    winw + ((q)&1)*512 + p*256); }

    // ---- 8-chunk pipeline, 2 chunks in flight, counted vmcnt (r12/r13) ----
    ISSUE(0)
    ISSUE(1)
    #pragma unroll
    for (int q = 0; q < 8; ++q) {
        if (q < 7) asm volatile("s_waitcnt vmcnt(2)" ::: "memory");
        else       asm volatile("s_waitcnt vmcnt(0)" ::: "memory");
        __builtin_amdgcn_sched_barrier(0);
        {
            const float* wb = winw + (q&1)*512;
            float f[4];
            #pragma unroll
            for (int u = 0; u < 4; ++u) {
                const float* wc = wb + (u>>1)*256 + (u&1)*128;
                f[u] = w00*wc[ro0] + w01*wc[ro0+1] + w10*wc[ro1] + w11*wc[ro1+1];
            }
            uint2 v;
            v.x = f2bf(f[0]) | (f2bf(f[1]) << 16);
            v.y = f2bf(f[2]) | (f2bf(f[3]) << 16);
            const int c = grp*32 + q*4;
            int byte = slot*256 + c*2;
            byte ^= (slot & 7) << 4;
            *reinterpret_cast<uint2*>(reinterpret_cast<char*>(lF) + byte) = v;
        }
        if (q < 6) {
            asm volatile("s_waitcnt lgkmcnt(0)" ::: "memory");
            __builtin_amdgcn_sched_barrier(0);
            ISSUE(q+2)
        }
    }
#undef ISSUE
    __syncthreads();

    // ---- GEMM (r13 verbatim): D[64px x 32ch]/wave = fea @ M^T, 2 class phases
    const int lo = xl & 15, hi = xl >> 4;
    f32x4 acc[2][4];   // [ch-tile t][px-tile nn]
    #pragma unroll
    for (int t = 0; t < 2; ++t)
        #pragma unroll
        for (int nn = 0; nn < 4; ++nn) acc[t][nn] = (f32x4){0.f, 0.f, 0.f, 0.f};

    #pragma unroll
    for (int ph = 0; ph < 2; ++ph) {            // class phase: nn = ph*2, ph*2+1
        const unsigned short* Mc = Mw + (size_t)(clsE | ph)*16384;
        s16x8 mf[2][4];                          // B-frags: col=lo (c_out), k=hi*8
        #pragma unroll
        for (int t = 0; t < 2; ++t)
            #pragma unroll
            for (int kk = 0; kk < 4; ++kk)
                mf[t][kk] = *reinterpret_cast<const s16x8*>(
                    Mc + (32*grp + 16*t + lo)*128 + kk*32 + hi*8);
        #pragma unroll
        for (int kk = 0; kk < 4; ++kk) {
            #pragma unroll
            for (int q2 = 0; q2 < 2; ++q2) {
                const int nn = ph*2 + q2;
                const int row = nn*16 + lo;      // A row = px slot
                int byte = row*256 + kk*64 + hi*16;
                byte ^= (row & 7) << 4;
                const s16x8 af = *reinterpret_cast<const s16x8*>(
                    reinterpret_cast<const char*>(lF) + byte);
                acc[0][nn] = __builtin_amdgcn_mfma_f32_16x16x32_bf16(af, mf[0][kk], acc[0][nn], 0, 0, 0);
                acc[1][nn] = __builtin_amdgcn_mfma_f32_16x16x32_bf16(af, mf[1][kk], acc[1][nn], 0, 0, 0);
            }
        }
    }

    // ---- NEW epilogue: transpose through LDS, then dense coalesced stores ----
    __syncthreads();                  // all lF reads done; reuse lds as lO
    float* lO = reinterpret_cast<float*>(ldsu);   // [128 ch][64 xgl], swizzled

    // D lane (lo,hi) reg r of tile (t,nn): ch = 32grp+16t+lo,
    // slot2 = nn*16 + hi*4 + r; xgl = slot2<32 ? 2*slot2 : 2*(slot2-32)+1.
    #pragma unroll
    for (int t = 0; t < 2; ++t) {
        const int ch = 32*grp + 16*t + lo;
        const int sw = (ch & 7) << 2;           // 4-float-chunk XOR swizzle
        #pragma unroll
        for (int nn = 0; nn < 4; ++nn) {
            #pragma unroll
            for (int r = 0; r < 4; ++r) {
                const int slot2 = nn*16 + hi*4 + r;
                const int xgl = (nn < 2) ? (2*slot2) : (2*(slot2 - 32) + 1);
                lO[ch*64 + (xgl ^ sw)] = acc[t][nn][r];
            }
        }
    }
    __syncthreads();

    // 8 rounds x dwordx4/thread: 16 consecutive tids cover one 256 B ch-row.
    #pragma unroll
    for (int k = 0; k < 8; ++k) {
        const int F  = tid*4 + k*1024;          // flat float index
        const int ch = F >> 6;
        const int m4 = F & 63;                  // aligned 4-float run base
        const int sw = (ch & 7) << 2;
        const f32x4 v = *reinterpret_cast<const f32x4*>(lO + ch*64 + (m4 ^ sw));
        float* op = out + ((size_t)(b*Cc + ch)*H2c + yg)*W2c + xt*64 + m4;
        *reinterpret_cast<f32x4*>(op) = v;
    }
}

extern "C" void kernel_launch(void* const* d_in, const int* in_sizes, int n_in,
                              void* d_out, int out_size, void* d_ws, size_t ws_size,
                              hipStream_t stream) {
    const float* x     = (const float*)d_in[0];
    const float* wcomp = (const float*)d_in[1];
    const float* wexp  = (const float*)d_in[2];
    const float* bw1   = (const float*)d_in[3];
    const float* bb1   = (const float*)d_in[4];
    const float* bw2   = (const float*)d_in[5];
    const float* bb2   = (const float*)d_in[6];
    const float* rw    = (const float*)d_in[7];
    const float* rb    = (const float*)d_in[8];
    const float* ow    = (const float*)d_in[9];
    const float* ob    = (const float*)d_in[10];
    float* out = (float*)d_out;
    float* ws  = (float*)d_ws;
    unsigned short* Mw = (unsigned short*)(ws + M_OFF);   // ~128 KB used

    k1_prep<<<64, 256, 0, stream>>>(wcomp, wexp, bw1, bb1, bw2, bb2,
                                    rw, rb, ow, ob, ws, Mw);
    k2_mfma<<<2304, 256, 0, stream>>>(x, ws, Mw, out);
}